// Round 8
// baseline (144.075 us; speedup 1.0000x reference)
//
#include <hip/hip_runtime.h>
#include <hip/hip_bf16.h>

#define NPTS 1048576
#define G1I  33
#define NV   35937     // 33^3
#define NC   32        // latent channels
#define HIDD 128

typedef _Float16 h8  __attribute__((ext_vector_type(8)));
typedef _Float16 h4  __attribute__((ext_vector_type(4)));
typedef __fp16   p2  __attribute__((ext_vector_type(2)));   // cvt_pkrtz return type
typedef float    f4  __attribute__((ext_vector_type(4)));

#define AS_GLOBAL(p) ((const __attribute__((address_space(1))) char*)(p))
#define AS_LDS(p)    ((__attribute__((address_space(3))) char*)(p))

// ws layout (bytes):
//   [0,     8192)  a1f: W1^T frags, 8 tiles * 64 lanes * 8 halves
//   [8192, 40960)  a2f: W2^T frags, 32 frags * 64 lanes * 8 halves
//   [40960, 45056) a3f: w3 A-frags (A3[m][k]=w3[k]), 4 frags * 64 lanes * 8 halves
//   [65536, 65536+NV*NC*2) embh: CHANNEL-PERMUTED corner rows [v][sigma(c)]
//     sigma(c) = ((c&12)<<1)|(c&3)|((c>>4)<<2): lane gq's B-frag channels
//     {4gq..4gq+3, 16+4gq..16+4gq+3} become the contiguous 16B chunk at gq*16.
#define WS_A1  0
#define WS_A2  8192
#define WS_A3  40960
#define WS_EMB 65536
#define WS_NEED (WS_EMB + NV*NC*2)

// MFMA 16x16x32 fragment k-map: elem i of lane l holds k = 16*(i>>2) + 4*(l>>4) + (i&3)
// D layout: col = lane&15, row = 4*(lane>>4) + reg.  Verified R1 (absmax 4.9e-4).

__global__ __launch_bounds__(256) void vox_prep(
    const float* __restrict__ emb, const float* __restrict__ w1,
    const float* __restrict__ w2, const float* __restrict__ w3,
    char* __restrict__ ws)
{
    __shared__ _Float16 tile[256][NC];
    const int b = blockIdx.x, t = threadIdx.x;
    _Float16* embh = (_Float16*)(ws + WS_EMB);
    if (b < 141) {
        const int v = b*256 + t;
        #pragma unroll
        for (int c = 0; c < NC; ++c) {
            float val = (v < NV) ? emb[c*NV + v] : 0.f;
            const int pos = ((c & 12) << 1) | (c & 3) | ((c >> 4) << 2);  // sigma(c)
            tile[t][pos] = (_Float16)val;
        }
        __syncthreads();
        if (v < NV) {
            uint4* dst = (uint4*)(embh + v*NC);
            const uint4* src = (const uint4*)&tile[t][0];
            #pragma unroll
            for (int j = 0; j < 4; ++j) dst[j] = src[j];
        }
    } else if (b < 149) {
        // W2^T frags: frag (t2*4+ks), lane l, elem i: k = 32*ks + 16*(i>>2) + 4*(l>>4) + (i&3)
        const int t2 = b - 141;
        const int ks = t >> 6, l = t & 63;
        const int gq = l >> 4, colh = l & 15;
        _Float16* a2f = (_Float16*)(ws + WS_A2);
        h8 fr;
        #pragma unroll
        for (int i = 0; i < 8; ++i) {
            const int k = 32*ks + 16*(i>>2) + 4*gq + (i&3);
            fr[i] = (_Float16)w2[k*HIDD + 16*t2 + colh];
        }
        *(h8*)(a2f + ((t2*4+ks)*64 + l)*8) = fr;
    } else if (b == 149) {
        // W1^T frags (k-map unchanged: permuted lat storage reproduces the standard B-frag)
        _Float16* a1f = (_Float16*)(ws + WS_A1);
        #pragma unroll
        for (int it = 0; it < 2; ++it) {
            const int item = t + it*256;
            const int t8 = item >> 6, l = item & 63;
            const int gq = l >> 4, colh = l & 15;
            h8 fr;
            #pragma unroll
            for (int i = 0; i < 8; ++i) {
                const int k = 16*(i>>2) + 4*gq + (i&3);
                fr[i] = (_Float16)w1[k*HIDD + 16*t8 + colh];
            }
            *(h8*)(a1f + (t8*64 + l)*8) = fr;
        }
    } else {
        // w3 A-frags: A3[m][k] = w3[k] (row-independent). frag j covers k = 32j..32j+32.
        _Float16* a3f = (_Float16*)(ws + WS_A3);
        const int j = t >> 6, l = t & 63;
        const int gq = l >> 4;
        h8 fr;
        #pragma unroll
        for (int i = 0; i < 8; ++i) {
            const int k = 32*j + 16*(i>>2) + 4*gq + (i&3);
            fr[i] = (_Float16)w3[k];
        }
        *(h8*)(a3f + (j*64 + l)*8) = fr;
    }
}

__global__ __launch_bounds__(256) void vox_main(
    const float* __restrict__ points, const char* __restrict__ ws,
    const float* __restrict__ b1, const float* __restrict__ b2,
    const float* __restrict__ b3v, float* __restrict__ out)
{
    __shared__ uint4 a2l[2048];          // 32 KB W2^T frags — the ONLY LDS now

    const int tid  = threadIdx.x;
    const int lane = tid & 63;
    const int wv   = tid >> 6;
    const int gq   = lane >> 4;
    const int colh = lane & 15;

    // ---- 0) W2-frag DMA first: overlaps with the whole gather+layer1 phase ----
    {
        const uint4* a2g = (const uint4*)(ws + WS_A2);
        #pragma unroll
        for (int j = 0; j < 8; ++j) {
            const uint4* gsrc = a2g + (j*256 + wv*64 + lane);      // per-lane global src
            uint4*       ldst = ((uint4*)a2l) + (j*256 + wv*64);   // wave-uniform LDS base
            __builtin_amdgcn_global_load_lds(
                (const __attribute__((address_space(1))) void*)AS_GLOBAL(gsrc),
                (__attribute__((address_space(3))) void*)AS_LDS(ldst),
                16, 0, 0);
        }
    }

    // ---- 1) own-point setup ----
    const char* embB = (const char*)(ws + WS_EMB);
    const int p = blockIdx.x*256 + tid;
    const float px = points[3*p+0], py = points[3*p+1], pz = points[3*p+2];
    const float xc = (px + 1.f)*16.f, yc = (py + 1.f)*16.f, zc = (pz + 1.f)*16.f;
    const float xf = floorf(xc), yf = floorf(yc), zf = floorf(zc);
    const float fx = xc - xf, fy = yc - yf, fz = zc - zf;
    // points uniform in [0,1) -> all 8 corners strictly in-bounds; no clamp/mask.
    const int vb = (((int)zf)*G1I + (int)yf)*G1I + (int)xf;

    // ---- persistent W1^T frags ----
    const h8* a1g = (const h8*)(ws + WS_A1);
    h8 a1fr[8];
    #pragma unroll
    for (int t8 = 0; t8 < 8; ++t8) a1fr[t8] = a1g[t8*64 + lane];

    // ---- 2) fused gather + layer 1, per pt-tile: each lane gathers ITS OWN B-frag ----
    // Corner c = z*4+y*2+x at byte offset z*69696 + y*2112 + x*64 (imm-foldable pairs).
    h8 B2f[4][4];   // [pt-tile][k-step] — layer-2 B-frags
    #pragma unroll
    for (int pt = 0; pt < 4; ++pt) {
        const int s = pt*16 + colh;               // wave-relative source point
        const float fxs = __shfl(fx, s);
        const float fys = __shfl(fy, s);
        const float fzs = __shfl(fz, s);
        const int   vbs = __shfl(vb, s);
        const char* bz0 = embB + (size_t)((unsigned)vbs*64u + (unsigned)gq*16u);
        const char* bz1 = bz0 + 69696;
        const h8 v0 = *(const h8*)(bz0 +    0);
        const h8 v1 = *(const h8*)(bz0 +   64);
        const h8 v2 = *(const h8*)(bz0 + 2112);
        const h8 v3 = *(const h8*)(bz0 + 2176);
        const h8 v4 = *(const h8*)(bz1 +    0);
        const h8 v5 = *(const h8*)(bz1 +   64);
        const h8 v6 = *(const h8*)(bz1 + 2112);
        const h8 v7 = *(const h8*)(bz1 + 2176);
        const float wx1 = fxs, wx0 = 1.f - fxs;
        const float wy1 = fys, wy0 = 1.f - fys;
        const float wz1 = fzs, wz0 = 1.f - fzs;
        h8 a = (h8){0,0,0,0,0,0,0,0};
        {   // same corner order/arithmetic as R1/R6/R7 -> bitwise-identical lat
            const _Float16 w0 = (_Float16)(wz0*wy0*wx0); const h8 W0 = {w0,w0,w0,w0,w0,w0,w0,w0}; a += W0*v0;
            const _Float16 w1_ = (_Float16)(wz0*wy0*wx1); const h8 W1 = {w1_,w1_,w1_,w1_,w1_,w1_,w1_,w1_}; a += W1*v1;
            const _Float16 w2_ = (_Float16)(wz0*wy1*wx0); const h8 W2 = {w2_,w2_,w2_,w2_,w2_,w2_,w2_,w2_}; a += W2*v2;
            const _Float16 w3_ = (_Float16)(wz0*wy1*wx1); const h8 W3 = {w3_,w3_,w3_,w3_,w3_,w3_,w3_,w3_}; a += W3*v3;
            const _Float16 w4_ = (_Float16)(wz1*wy0*wx0); const h8 W4 = {w4_,w4_,w4_,w4_,w4_,w4_,w4_,w4_}; a += W4*v4;
            const _Float16 w5_ = (_Float16)(wz1*wy0*wx1); const h8 W5 = {w5_,w5_,w5_,w5_,w5_,w5_,w5_,w5_}; a += W5*v5;
            const _Float16 w6_ = (_Float16)(wz1*wy1*wx0); const h8 W6 = {w6_,w6_,w6_,w6_,w6_,w6_,w6_,w6_}; a += W6*v6;
            const _Float16 w7_ = (_Float16)(wz1*wy1*wx1); const h8 W7 = {w7_,w7_,w7_,w7_,w7_,w7_,w7_,w7_}; a += W7*v7;
        }
        // ---- layer 1 for this pt: a IS the B-frag (channel permutation by design) ----
        f4 acc1[8];
        #pragma unroll
        for (int t8 = 0; t8 < 8; ++t8) acc1[t8] = *(const f4*)(b1 + 16*t8 + 4*gq);
        #pragma unroll
        for (int t8 = 0; t8 < 8; ++t8)
            acc1[t8] = __builtin_amdgcn_mfma_f32_16x16x32_f16(a1fr[t8], a, acc1[t8], 0, 0, 0);
        #pragma unroll
        for (int ks = 0; ks < 4; ++ks) {
            union { h8 v; p2 h[4]; } u;
            const p2 z = {(__fp16)0, (__fp16)0};
            u.h[0] = __builtin_elementwise_max(__builtin_amdgcn_cvt_pkrtz(acc1[2*ks  ][0], acc1[2*ks  ][1]), z);
            u.h[1] = __builtin_elementwise_max(__builtin_amdgcn_cvt_pkrtz(acc1[2*ks  ][2], acc1[2*ks  ][3]), z);
            u.h[2] = __builtin_elementwise_max(__builtin_amdgcn_cvt_pkrtz(acc1[2*ks+1][0], acc1[2*ks+1][1]), z);
            u.h[3] = __builtin_elementwise_max(__builtin_amdgcn_cvt_pkrtz(acc1[2*ks+1][2], acc1[2*ks+1][3]), z);
            B2f[pt][ks] = u.v;
        }
    }

    // ---- barrier: own DMAs drained (vmcnt 0) + all waves' DMAs done ----
    asm volatile("s_waitcnt vmcnt(0)" ::: "memory");
    __syncthreads();

    // ---- layer 2: D2 = W2^T @ h1^T (+b2), relu+pack per t2-pair; layer 3 via MFMA ----
    const h8* a3g = (const h8*)(ws + WS_A3);
    f4 acc3[4];
    #pragma unroll
    for (int pt = 0; pt < 4; ++pt) acc3[pt] = (f4){0.f,0.f,0.f,0.f};
    #pragma unroll
    for (int q2 = 0; q2 < 4; ++q2) {
        const f4 b2e = *(const f4*)(b2 + 16*(2*q2  ) + 4*gq);
        const f4 b2o = *(const f4*)(b2 + 16*(2*q2+1) + 4*gq);
        f4 acc2e[4], acc2o[4];
        #pragma unroll
        for (int pt = 0; pt < 4; ++pt) { acc2e[pt] = b2e; acc2o[pt] = b2o; }
        #pragma unroll
        for (int ks = 0; ks < 4; ++ks) {
            const h8 fe = *(const h8*)&a2l[((2*q2  )*4 + ks)*64 + lane];
            #pragma unroll
            for (int pt = 0; pt < 4; ++pt)
                acc2e[pt] = __builtin_amdgcn_mfma_f32_16x16x32_f16(fe, B2f[pt][ks], acc2e[pt], 0, 0, 0);
        }
        #pragma unroll
        for (int ks = 0; ks < 4; ++ks) {
            const h8 fo = *(const h8*)&a2l[((2*q2+1)*4 + ks)*64 + lane];
            #pragma unroll
            for (int pt = 0; pt < 4; ++pt)
                acc2o[pt] = __builtin_amdgcn_mfma_f32_16x16x32_f16(fo, B2f[pt][ks], acc2o[pt], 0, 0, 0);
        }
        // pack h2 (relu) -> B3 frag for k-slice q2; dot with w3 on the MFMA pipe
        const h8 a3fr = a3g[q2*64 + lane];
        #pragma unroll
        for (int pt = 0; pt < 4; ++pt) {
            union { h8 v; p2 h[4]; } u;
            const p2 z = {(__fp16)0, (__fp16)0};
            u.h[0] = __builtin_elementwise_max(__builtin_amdgcn_cvt_pkrtz(acc2e[pt][0], acc2e[pt][1]), z);
            u.h[1] = __builtin_elementwise_max(__builtin_amdgcn_cvt_pkrtz(acc2e[pt][2], acc2e[pt][3]), z);
            u.h[2] = __builtin_elementwise_max(__builtin_amdgcn_cvt_pkrtz(acc2o[pt][0], acc2o[pt][1]), z);
            u.h[3] = __builtin_elementwise_max(__builtin_amdgcn_cvt_pkrtz(acc2o[pt][2], acc2o[pt][3]), z);
            acc3[pt] = __builtin_amdgcn_mfma_f32_16x16x32_f16(a3fr, u.v, acc3[pt], 0, 0, 0);
        }
    }

    // D3 rows are identical (A3 row-independent): lane's own point (pt==gq, col==colh)
    float sv = 0.f;
    #pragma unroll
    for (int pt = 0; pt < 4; ++pt) if (gq == pt) sv = acc3[pt][0];
    const float zi = sv + b3v[0];
    const float e  = __expf(2.f*zi);
    out[blockIdx.x*256 + tid] = (e - 1.f) / (e + 1.f);
}

extern "C" void kernel_launch(void* const* d_in, const int* in_sizes, int n_in,
                              void* d_out, int out_size, void* d_ws, size_t ws_size,
                              hipStream_t stream)
{
    const float* points = (const float*)d_in[0];
    const float* emb    = (const float*)d_in[1];
    const float* w1     = (const float*)d_in[2];
    const float* b1     = (const float*)d_in[3];
    const float* w2     = (const float*)d_in[4];
    const float* b2     = (const float*)d_in[5];
    const float* w3     = (const float*)d_in[6];
    const float* b3     = (const float*)d_in[7];
    float* out = (float*)d_out;
    char*  ws  = (char*)d_ws;
    if (ws_size < (size_t)WS_NEED) return;  // fail visibly rather than corrupt memory

    hipLaunchKernelGGL(vox_prep, dim3(151), dim3(256), 0, stream, emb, w1, w2, w3, ws);
    hipLaunchKernelGGL(vox_main, dim3(NPTS/256), dim3(256), 0, stream,
                       points, ws, b1, b2, b3, out);
}

// Round 9
// 132.119 us; speedup vs baseline: 1.0905x; 1.0905x over previous
//
#include <hip/hip_runtime.h>
#include <hip/hip_bf16.h>

#define NPTS 1048576
#define G1I  33
#define NV   35937     // 33^3
#define NC   32        // latent channels
#define HIDD 128

typedef _Float16 h8  __attribute__((ext_vector_type(8)));
typedef __fp16   p2  __attribute__((ext_vector_type(2)));   // cvt_pkrtz return type
typedef float    f4  __attribute__((ext_vector_type(4)));

#define AS_GLOBAL(p) ((const __attribute__((address_space(1))) char*)(p))
#define AS_LDS(p)    ((__attribute__((address_space(3))) char*)(p))

// ws layout (bytes):
//   [0,     8192)  a1f: W1^T frags, 8 tiles * 64 lanes * 8 halves
//   [8192, 40960)  a2f: W2^T frags, 32 frags * 64 lanes * 8 halves
//   [40960, 45056) a3f: w3 A-frags (A3[m][k]=w3[k]), 4 frags * 64 lanes * 8 halves
//   [65536, 65536+NV*NC*2) embh: CHANNEL-PERMUTED corner rows [v][sigma(c)]
//     sigma(c) = ((c&12)<<1)|(c&3)|((c>>4)<<2): lane gq's B-frag channels
//     {4gq..4gq+3, 16+4gq..16+4gq+3} are the contiguous 16B chunk at byte gq*16.
//     (HW-verified R8: direct B-frag consumption passed bit-identical.)
#define WS_A1  0
#define WS_A2  8192
#define WS_A3  40960
#define WS_EMB 65536
#define WS_NEED (WS_EMB + NV*NC*2)

// MFMA 16x16x32 fragment k-map: elem i of lane l holds k = 16*(i>>2) + 4*(l>>4) + (i&3)
// D layout: col = lane&15, row = 4*(lane>>4) + reg.  Verified R1 (absmax 4.9e-4).

__global__ __launch_bounds__(256) void vox_prep(
    const float* __restrict__ emb, const float* __restrict__ w1,
    const float* __restrict__ w2, const float* __restrict__ w3,
    char* __restrict__ ws)
{
    __shared__ _Float16 tile[256][NC];
    const int b = blockIdx.x, t = threadIdx.x;
    _Float16* embh = (_Float16*)(ws + WS_EMB);
    if (b < 141) {
        const int v = b*256 + t;
        #pragma unroll
        for (int c = 0; c < NC; ++c) {
            float val = (v < NV) ? emb[c*NV + v] : 0.f;
            const int pos = ((c & 12) << 1) | (c & 3) | ((c >> 4) << 2);  // sigma(c)
            tile[t][pos] = (_Float16)val;
        }
        __syncthreads();
        if (v < NV) {
            uint4* dst = (uint4*)(embh + v*NC);
            const uint4* src = (const uint4*)&tile[t][0];
            #pragma unroll
            for (int j = 0; j < 4; ++j) dst[j] = src[j];
        }
    } else if (b < 149) {
        // W2^T frags: frag (t2*4+ks), lane l, elem i: k = 32*ks + 16*(i>>2) + 4*(l>>4) + (i&3)
        const int t2 = b - 141;
        const int ks = t >> 6, l = t & 63;
        const int gq = l >> 4, colh = l & 15;
        _Float16* a2f = (_Float16*)(ws + WS_A2);
        h8 fr;
        #pragma unroll
        for (int i = 0; i < 8; ++i) {
            const int k = 32*ks + 16*(i>>2) + 4*gq + (i&3);
            fr[i] = (_Float16)w2[k*HIDD + 16*t2 + colh];
        }
        *(h8*)(a2f + ((t2*4+ks)*64 + l)*8) = fr;
    } else if (b == 149) {
        // W1^T frags (k-map unchanged: permuted lat storage reproduces the standard B-frag)
        _Float16* a1f = (_Float16*)(ws + WS_A1);
        #pragma unroll
        for (int it = 0; it < 2; ++it) {
            const int item = t + it*256;
            const int t8 = item >> 6, l = item & 63;
            const int gq = l >> 4, colh = l & 15;
            h8 fr;
            #pragma unroll
            for (int i = 0; i < 8; ++i) {
                const int k = 16*(i>>2) + 4*gq + (i&3);
                fr[i] = (_Float16)w1[k*HIDD + 16*t8 + colh];
            }
            *(h8*)(a1f + (t8*64 + l)*8) = fr;
        }
    } else {
        // w3 A-frags: A3[m][k] = w3[k] (row-independent). frag j covers k = 32j..32j+32.
        _Float16* a3f = (_Float16*)(ws + WS_A3);
        const int j = t >> 6, l = t & 63;
        const int gq = l >> 4;
        h8 fr;
        #pragma unroll
        for (int i = 0; i < 8; ++i) {
            const int k = 32*j + 16*(i>>2) + 4*gq + (i&3);
            fr[i] = (_Float16)w3[k];
        }
        *(h8*)(a3f + (j*64 + l)*8) = fr;
    }
}

// 512 threads/block (8 waves): latl 40KB + a2l 32KB = 72KB -> 2 blocks/CU = 16 waves/CU
__global__ __launch_bounds__(512) void vox_main(
    const float* __restrict__ points, const char* __restrict__ ws,
    const float* __restrict__ b1, const float* __restrict__ b2,
    const float* __restrict__ b3v, float* __restrict__ out)
{
    __shared__ _Float16 latl[512][40];   // 80B rows: 16B-aligned b128; chunks at byte gq*16
    __shared__ uint4    a2l[2048];       // 32 KB W2^T frags (DMA'd at kernel start)

    const int tid  = threadIdx.x;        // 0..511
    const int lane = tid & 63;
    const int wv   = tid >> 6;           // 0..7
    const int gq   = lane >> 4;
    const int colh = lane & 15;

    // ---- 0) W2-frag DMA first: overlaps with the whole gather+layer1 phase ----
    {
        const uint4* a2g = (const uint4*)(ws + WS_A2);
        #pragma unroll
        for (int j = 0; j < 4; ++j) {
            const uint4* gsrc = a2g + (j*512 + tid);               // per-lane global src
            uint4*       ldst = ((uint4*)a2l) + (j*512 + wv*64);   // wave-uniform LDS base
            __builtin_amdgcn_global_load_lds(
                (const __attribute__((address_space(1))) void*)AS_GLOBAL(gsrc),
                (__attribute__((address_space(3))) void*)AS_LDS(ldst),
                16, 0, 0);
        }
    }

    // ---- 1) own-point setup ----
    const char* embB = (const char*)(ws + WS_EMB);
    const int p = blockIdx.x*512 + tid;
    const float px = points[3*p+0], py = points[3*p+1], pz = points[3*p+2];
    const float xc = (px + 1.f)*16.f, yc = (py + 1.f)*16.f, zc = (pz + 1.f)*16.f;
    const float xf = floorf(xc), yf = floorf(yc), zf = floorf(zc);
    const float fx = xc - xf, fy = yc - yf, fz = zc - zf;
    // points uniform in [0,1) -> all 8 corners strictly in-bounds; no clamp/mask.
    const int vb = (((int)zf)*G1I + (int)yf)*G1I + (int)xf;

    // ---- 2) cooperative gather: 4 lanes split one 64B permuted row (16 lines/inst) ----
    // Corner c = z*4+y*2+x at byte offset z*69696 + y*2112 + x*64 (imm-foldable pairs).
    // Permutation is invisible here: rows treated as opaque 16B chunks, same corner
    // order/arithmetic as R1/R6/R7 -> lat values bit-identical (stored permuted).
    const int q  = lane >> 2;    // source point (within 16-group) this lane serves
    const int ch = lane & 3;     // 16B chunk of the permuted row
    h8 accch[4];
    #pragma unroll
    for (int sh = 0; sh < 4; ++sh) {
        const int s = sh*16 + q;                    // wave-relative source point
        const float fxs = __shfl(fx, s);
        const float fys = __shfl(fy, s);
        const float fzs = __shfl(fz, s);
        const int   vbs = __shfl(vb, s);
        const char* bz0 = embB + (size_t)((unsigned)vbs*64u + (unsigned)ch*16u);
        const char* bz1 = bz0 + 69696;
        const h8 v0 = *(const h8*)(bz0 +    0);
        const h8 v1 = *(const h8*)(bz0 +   64);
        const h8 v2 = *(const h8*)(bz0 + 2112);
        const h8 v3 = *(const h8*)(bz0 + 2176);
        const h8 v4 = *(const h8*)(bz1 +    0);
        const h8 v5 = *(const h8*)(bz1 +   64);
        const h8 v6 = *(const h8*)(bz1 + 2112);
        const h8 v7 = *(const h8*)(bz1 + 2176);
        const float wx1 = fxs, wx0 = 1.f - fxs;
        const float wy1 = fys, wy0 = 1.f - fys;
        const float wz1 = fzs, wz0 = 1.f - fzs;
        h8 a = (h8){0,0,0,0,0,0,0,0};
        {
            const _Float16 w0 = (_Float16)(wz0*wy0*wx0); const h8 W0 = {w0,w0,w0,w0,w0,w0,w0,w0}; a += W0*v0;
            const _Float16 w1_ = (_Float16)(wz0*wy0*wx1); const h8 W1 = {w1_,w1_,w1_,w1_,w1_,w1_,w1_,w1_}; a += W1*v1;
            const _Float16 w2_ = (_Float16)(wz0*wy1*wx0); const h8 W2 = {w2_,w2_,w2_,w2_,w2_,w2_,w2_,w2_}; a += W2*v2;
            const _Float16 w3_ = (_Float16)(wz0*wy1*wx1); const h8 W3 = {w3_,w3_,w3_,w3_,w3_,w3_,w3_,w3_}; a += W3*v3;
            const _Float16 w4_ = (_Float16)(wz1*wy0*wx0); const h8 W4 = {w4_,w4_,w4_,w4_,w4_,w4_,w4_,w4_}; a += W4*v4;
            const _Float16 w5_ = (_Float16)(wz1*wy0*wx1); const h8 W5 = {w5_,w5_,w5_,w5_,w5_,w5_,w5_,w5_}; a += W5*v5;
            const _Float16 w6_ = (_Float16)(wz1*wy1*wx0); const h8 W6 = {w6_,w6_,w6_,w6_,w6_,w6_,w6_,w6_}; a += W6*v6;
            const _Float16 w7_ = (_Float16)(wz1*wy1*wx1); const h8 W7 = {w7_,w7_,w7_,w7_,w7_,w7_,w7_,w7_}; a += W7*v7;
        }
        accch[sh] = a;
    }
    // ---- 3) write chunks to latl (intra-wave rows only) ----
    #pragma unroll
    for (int sh = 0; sh < 4; ++sh)
        *(uint4*)&latl[wv*64 + sh*16 + q][8*ch] = *(uint4*)&accch[sh];
    // DS pipe is in-order per wave; reads below touch only this wave's rows. (validated R4-R7)
    asm volatile("s_waitcnt lgkmcnt(0)" ::: "memory");

    // ---- persistent W1^T frags ----
    const h8* a1g = (const h8*)(ws + WS_A1);
    h8 a1fr[8];
    #pragma unroll
    for (int t8 = 0; t8 < 8; ++t8) a1fr[t8] = a1g[t8*64 + lane];

    // ---- layer 1: B-frag is ONE b128 read (sigma layout), MFMA, relu-pack -> B2 frags ----
    h8 B2f[4][4];   // [pt-tile][k-step]
    #pragma unroll
    for (int pt = 0; pt < 4; ++pt) {
        const h8 bf = *(const h8*)&latl[wv*64 + pt*16 + colh][8*gq];
        f4 acc1[8];
        #pragma unroll
        for (int t8 = 0; t8 < 8; ++t8) acc1[t8] = *(const f4*)(b1 + 16*t8 + 4*gq);
        #pragma unroll
        for (int t8 = 0; t8 < 8; ++t8)
            acc1[t8] = __builtin_amdgcn_mfma_f32_16x16x32_f16(a1fr[t8], bf, acc1[t8], 0, 0, 0);
        #pragma unroll
        for (int ks = 0; ks < 4; ++ks) {
            union { h8 v; p2 h[4]; } u;
            const p2 z = {(__fp16)0, (__fp16)0};
            u.h[0] = __builtin_elementwise_max(__builtin_amdgcn_cvt_pkrtz(acc1[2*ks  ][0], acc1[2*ks  ][1]), z);
            u.h[1] = __builtin_elementwise_max(__builtin_amdgcn_cvt_pkrtz(acc1[2*ks  ][2], acc1[2*ks  ][3]), z);
            u.h[2] = __builtin_elementwise_max(__builtin_amdgcn_cvt_pkrtz(acc1[2*ks+1][0], acc1[2*ks+1][1]), z);
            u.h[3] = __builtin_elementwise_max(__builtin_amdgcn_cvt_pkrtz(acc1[2*ks+1][2], acc1[2*ks+1][3]), z);
            B2f[pt][ks] = u.v;
        }
    }

    // ---- barrier: own DMAs drained (vmcnt 0) + all waves' DMAs done ----
    asm volatile("s_waitcnt vmcnt(0)" ::: "memory");
    __syncthreads();

    // ---- layer 2: D2 = W2^T @ h1^T (+b2), relu+pack per t2-pair; layer 3 via MFMA ----
    const h8* a3g = (const h8*)(ws + WS_A3);
    f4 acc3[4];
    #pragma unroll
    for (int pt = 0; pt < 4; ++pt) acc3[pt] = (f4){0.f,0.f,0.f,0.f};
    #pragma unroll
    for (int q2 = 0; q2 < 4; ++q2) {
        const f4 b2e = *(const f4*)(b2 + 16*(2*q2  ) + 4*gq);
        const f4 b2o = *(const f4*)(b2 + 16*(2*q2+1) + 4*gq);
        f4 acc2e[4], acc2o[4];
        #pragma unroll
        for (int pt = 0; pt < 4; ++pt) { acc2e[pt] = b2e; acc2o[pt] = b2o; }
        #pragma unroll
        for (int ks = 0; ks < 4; ++ks) {
            const h8 fe = *(const h8*)&a2l[((2*q2  )*4 + ks)*64 + lane];
            #pragma unroll
            for (int pt = 0; pt < 4; ++pt)
                acc2e[pt] = __builtin_amdgcn_mfma_f32_16x16x32_f16(fe, B2f[pt][ks], acc2e[pt], 0, 0, 0);
        }
        #pragma unroll
        for (int ks = 0; ks < 4; ++ks) {
            const h8 fo = *(const h8*)&a2l[((2*q2+1)*4 + ks)*64 + lane];
            #pragma unroll
            for (int pt = 0; pt < 4; ++pt)
                acc2o[pt] = __builtin_amdgcn_mfma_f32_16x16x32_f16(fo, B2f[pt][ks], acc2o[pt], 0, 0, 0);
        }
        // pack h2 (relu) -> B3 frag for k-slice q2; dot with w3 on the MFMA pipe
        const h8 a3fr = a3g[q2*64 + lane];
        #pragma unroll
        for (int pt = 0; pt < 4; ++pt) {
            union { h8 v; p2 h[4]; } u;
            const p2 z = {(__fp16)0, (__fp16)0};
            u.h[0] = __builtin_elementwise_max(__builtin_amdgcn_cvt_pkrtz(acc2e[pt][0], acc2e[pt][1]), z);
            u.h[1] = __builtin_elementwise_max(__builtin_amdgcn_cvt_pkrtz(acc2e[pt][2], acc2e[pt][3]), z);
            u.h[2] = __builtin_elementwise_max(__builtin_amdgcn_cvt_pkrtz(acc2o[pt][0], acc2o[pt][1]), z);
            u.h[3] = __builtin_elementwise_max(__builtin_amdgcn_cvt_pkrtz(acc2o[pt][2], acc2o[pt][3]), z);
            acc3[pt] = __builtin_amdgcn_mfma_f32_16x16x32_f16(a3fr, u.v, acc3[pt], 0, 0, 0);
        }
    }

    // D3 rows are identical (A3 row-independent): lane's own point (pt==gq, col==colh)
    float sv = 0.f;
    #pragma unroll
    for (int pt = 0; pt < 4; ++pt) if (gq == pt) sv = acc3[pt][0];
    const float zi = sv + b3v[0];
    const float e  = __expf(2.f*zi);
    out[blockIdx.x*512 + tid] = (e - 1.f) / (e + 1.f);
}

extern "C" void kernel_launch(void* const* d_in, const int* in_sizes, int n_in,
                              void* d_out, int out_size, void* d_ws, size_t ws_size,
                              hipStream_t stream)
{
    const float* points = (const float*)d_in[0];
    const float* emb    = (const float*)d_in[1];
    const float* w1     = (const float*)d_in[2];
    const float* b1     = (const float*)d_in[3];
    const float* w2     = (const float*)d_in[4];
    const float* b2     = (const float*)d_in[5];
    const float* w3     = (const float*)d_in[6];
    const float* b3     = (const float*)d_in[7];
    float* out = (float*)d_out;
    char*  ws  = (char*)d_ws;
    if (ws_size < (size_t)WS_NEED) return;  // fail visibly rather than corrupt memory

    hipLaunchKernelGGL(vox_prep, dim3(151), dim3(256), 0, stream, emb, w1, w2, w3, ws);
    hipLaunchKernelGGL(vox_main, dim3(NPTS/512), dim3(512), 0, stream,
                       points, ws, b1, b2, b3, out);
}